// Round 2
// baseline (1364.920 us; speedup 1.0000x reference)
//
#include <hip/hip_runtime.h>
#include <hip/hip_bf16.h>
#include <math.h>

#define N_NODES 50000
#define N_EDGES 500000
#define H_DIM   128
#define BN_EPS  1e-5f

// ---------------------------------------------------------------------------
// Kernel A: per-edge dot(e_src, e_dst) -> ex = exp(score) (f64); denom[dst]+=ex
// 32 lanes per edge, float4 loads (32*16B = 512B = one row).
// f64 exp/sum: self-loop edges score ~128 (chi^2), expf overflows fp32;
// double is exact-enough and removes the need for a segment-max pass.
// ---------------------------------------------------------------------------
__global__ __launch_bounds__(256) void edge_exp_kernel(
    const float* __restrict__ emb,
    const int* __restrict__ src,
    const int* __restrict__ dst,
    double* __restrict__ ex,
    double* __restrict__ denom)
{
    int gid  = blockIdx.x * blockDim.x + threadIdx.x;
    int edge = gid >> 5;
    int lane = threadIdx.x & 31;
    if (edge >= N_EDGES) return;

    int s = src[edge];
    int d = dst[edge];
    const float4* srow = (const float4*)(emb + (size_t)s * H_DIM);
    const float4* drow = (const float4*)(emb + (size_t)d * H_DIM);
    float4 a = srow[lane];
    float4 b = drow[lane];
    float p = a.x * b.x + a.y * b.y + a.z * b.z + a.w * b.w;
    #pragma unroll
    for (int off = 16; off > 0; off >>= 1)
        p += __shfl_xor(p, off);
    if (lane == 0) {
        double e = exp((double)p);   // max |p| <= max ||x||^2 ~ 210 << 709
        ex[edge] = e;
        unsafeAtomicAdd(denom + d, e);
    }
}

// ---------------------------------------------------------------------------
// Kernel B: norm = ex/denom[dst] (f64 ratio -> f32); neigh[dst] += e_src*norm
// ---------------------------------------------------------------------------
__global__ __launch_bounds__(256) void edge_scatter_kernel(
    const float* __restrict__ emb,
    const int* __restrict__ src,
    const int* __restrict__ dst,
    const double* __restrict__ ex,
    const double* __restrict__ denom,
    float* __restrict__ neigh)
{
    int gid  = blockIdx.x * blockDim.x + threadIdx.x;
    int edge = gid >> 5;
    int lane = threadIdx.x & 31;
    if (edge >= N_EDGES) return;

    int s = src[edge];
    int d = dst[edge];
    float norm = (float)(ex[edge] / denom[d]);
    const float4* srow = (const float4*)(emb + (size_t)s * H_DIM);
    float4 a = srow[lane];
    float* nrow = neigh + (size_t)d * H_DIM + lane * 4;
    unsafeAtomicAdd(nrow + 0, a.x * norm);
    unsafeAtomicAdd(nrow + 1, a.y * norm);
    unsafeAtomicAdd(nrow + 2, a.z * norm);
    unsafeAtomicAdd(nrow + 3, a.w * norm);
}

// ---------------------------------------------------------------------------
// Kernel C: h = neigh @ W  (fp32 vector GEMM, 32x128 block tile, 4x4 reg tile)
// + per-column sum / sumsq partials via one atomic per thread at the end.
// LDS: W 64KB + A-tile 16KB = 80KB -> 2 blocks/CU.
// ---------------------------------------------------------------------------
__global__ __launch_bounds__(256) void gemm_stats_kernel(
    const float* __restrict__ neigh,
    const float* __restrict__ W,
    float* __restrict__ h,
    float* __restrict__ colsum,
    float* __restrict__ colsq)
{
    __shared__ float Ws[128][128];   // 64 KB
    __shared__ float As[32][128];    // 16 KB

    int t  = threadIdx.x;
    int tx = t & 31;                 // column group: cols 4*tx .. 4*tx+3
    int ty = t >> 5;                 // row group:    rows 4*ty .. 4*ty+3

    for (int i = t; i < 128 * 128; i += 256)
        Ws[i >> 7][i & 127] = W[i];

    float csum[4] = {0.f, 0.f, 0.f, 0.f};
    float csq[4]  = {0.f, 0.f, 0.f, 0.f};

    for (int r0 = blockIdx.x * 32; r0 < N_NODES; r0 += gridDim.x * 32) {
        __syncthreads();
        for (int i = t; i < 32 * 128; i += 256) {
            int r = i >> 7, k = i & 127;
            int gr = r0 + r;
            As[r][k] = (gr < N_NODES) ? neigh[(size_t)gr * H_DIM + k] : 0.f;
        }
        __syncthreads();

        float acc[4][4];
        #pragma unroll
        for (int i = 0; i < 4; ++i)
            #pragma unroll
            for (int j = 0; j < 4; ++j)
                acc[i][j] = 0.f;

        #pragma unroll 8
        for (int k = 0; k < 128; ++k) {
            float4 w = *(const float4*)(&Ws[k][tx * 4]);
            #pragma unroll
            for (int i = 0; i < 4; ++i) {
                float a = As[ty * 4 + i][k];
                acc[i][0] += a * w.x;
                acc[i][1] += a * w.y;
                acc[i][2] += a * w.z;
                acc[i][3] += a * w.w;
            }
        }

        #pragma unroll
        for (int i = 0; i < 4; ++i) {
            int gr = r0 + ty * 4 + i;
            if (gr < N_NODES) {
                float4 out;
                out.x = acc[i][0]; out.y = acc[i][1];
                out.z = acc[i][2]; out.w = acc[i][3];
                *(float4*)(h + (size_t)gr * H_DIM + tx * 4) = out;
                #pragma unroll
                for (int j = 0; j < 4; ++j) {
                    csum[j] += acc[i][j];
                    csq[j]  += acc[i][j] * acc[i][j];
                }
            }
        }
    }

    #pragma unroll
    for (int j = 0; j < 4; ++j) {
        unsafeAtomicAdd(colsum + tx * 4 + j, csum[j]);
        unsafeAtomicAdd(colsq  + tx * 4 + j, csq[j]);
    }
}

// ---------------------------------------------------------------------------
// Kernel D: fold BN stats into per-column scale/shift (1 block, 128 threads)
// ---------------------------------------------------------------------------
__global__ void bn_stats_kernel(
    const float* __restrict__ colsum,
    const float* __restrict__ colsq,
    const float* __restrict__ gamma,
    const float* __restrict__ beta,
    float* __restrict__ scale,
    float* __restrict__ shift)
{
    int c = threadIdx.x;
    const float invN = 1.0f / (float)N_NODES;
    float mu  = colsum[c] * invN;
    float var = colsq[c] * invN - mu * mu;   // biased, matches jnp.var
    float sc  = gamma[c] * rsqrtf(var + BN_EPS);
    scale[c] = sc;
    shift[c] = beta[c] - mu * sc;
}

// ---------------------------------------------------------------------------
// Kernel E: out = tanh(h * scale[c] + shift[c]), in place on d_out
// ---------------------------------------------------------------------------
__global__ __launch_bounds__(256) void bn_tanh_kernel(
    float* __restrict__ h,
    const float* __restrict__ scale,
    const float* __restrict__ shift)
{
    size_t i = (size_t)blockIdx.x * blockDim.x + threadIdx.x;
    size_t idx4 = i * 4;
    if (idx4 >= (size_t)N_NODES * H_DIM) return;
    int c = (int)(idx4 & (H_DIM - 1));
    float4 v = *(float4*)(h + idx4);
    v.x = tanhf(v.x * scale[c + 0] + shift[c + 0]);
    v.y = tanhf(v.y * scale[c + 1] + shift[c + 1]);
    v.z = tanhf(v.z * scale[c + 2] + shift[c + 2]);
    v.w = tanhf(v.w * scale[c + 3] + shift[c + 3]);
    *(float4*)(h + idx4) = v;
}

// ---------------------------------------------------------------------------
extern "C" void kernel_launch(void* const* d_in, const int* in_sizes, int n_in,
                              void* d_out, int out_size, void* d_ws, size_t ws_size,
                              hipStream_t stream)
{
    const float* ent_emb = (const float*)d_in[0];
    const float* neigh_w = (const float*)d_in[1];
    const float* gamma   = (const float*)d_in[2];
    const float* beta    = (const float*)d_in[3];
    const int*   src     = (const int*)d_in[4];
    const int*   dst     = (const int*)d_in[5];
    float* out = (float*)d_out;

    char* ws = (char*)d_ws;
    float*  neigh  = (float*)ws;                                   // 25.6 MB
    double* ex     = (double*)(ws + (size_t)N_NODES * H_DIM * 4);  //  4.0 MB
    double* denom  = ex + N_EDGES;                                 //  0.4 MB
    float*  colsum = (float*)(denom + N_NODES);
    float*  colsq  = colsum + H_DIM;
    float*  scale  = colsq + H_DIM;
    float*  shift  = scale + H_DIM;

    hipMemsetAsync(neigh, 0, (size_t)N_NODES * H_DIM * sizeof(float), stream);
    hipMemsetAsync(denom, 0, (size_t)N_NODES * sizeof(double), stream);
    hipMemsetAsync(colsum, 0, 2 * H_DIM * sizeof(float), stream);

    {
        int threads_total = N_EDGES * 32;
        int blocks = (threads_total + 255) / 256;
        edge_exp_kernel<<<blocks, 256, 0, stream>>>(ent_emb, src, dst, ex, denom);
        edge_scatter_kernel<<<blocks, 256, 0, stream>>>(ent_emb, src, dst, ex, denom, neigh);
    }
    gemm_stats_kernel<<<512, 256, 0, stream>>>(neigh, neigh_w, out, colsum, colsq);
    bn_stats_kernel<<<1, 128, 0, stream>>>(colsum, colsq, gamma, beta, scale, shift);
    {
        size_t total4 = (size_t)N_NODES * H_DIM / 4;
        int blocks = (int)((total4 + 255) / 256);
        bn_tanh_kernel<<<blocks, 256, 0, stream>>>(out, scale, shift);
    }
}

// Round 3
// 729.140 us; speedup vs baseline: 1.8720x; 1.8720x over previous
//
#include <hip/hip_runtime.h>
#include <hip/hip_bf16.h>
#include <math.h>

#define N_NODES 50000
#define N_EDGES 500000
#define H_DIM   128
#define BN_EPS  1e-5f

// ---------------------------------------------------------------------------
// K1: histogram of dst -> deg[]
// ---------------------------------------------------------------------------
__global__ __launch_bounds__(256) void hist_kernel(
    const int* __restrict__ dst, int* __restrict__ deg)
{
    int e = blockIdx.x * blockDim.x + threadIdx.x;
    if (e < N_EDGES) atomicAdd(&deg[dst[e]], 1);
}

// ---------------------------------------------------------------------------
// K2: exclusive prefix sum of deg -> rowptr[0..N], cursor (copy). One block.
// 1024 threads x 49-element serial chunks + Hillis-Steele block scan.
// ---------------------------------------------------------------------------
__global__ __launch_bounds__(1024) void scan_kernel(
    const int* __restrict__ deg, int* __restrict__ rowptr, int* __restrict__ cursor)
{
    __shared__ int sums[1024];
    int t = threadIdx.x;
    const int CH = (N_NODES + 1023) / 1024;   // 49
    int beg = t * CH;
    int end = min(beg + CH, N_NODES);
    int s = 0;
    for (int i = beg; i < end; ++i) s += deg[i];
    sums[t] = s;
    __syncthreads();
    for (int off = 1; off < 1024; off <<= 1) {
        int v = (t >= off) ? sums[t - off] : 0;
        __syncthreads();
        sums[t] += v;
        __syncthreads();
    }
    int base = (t == 0) ? 0 : sums[t - 1];    // exclusive prefix
    for (int i = beg; i < end; ++i) {
        rowptr[i] = base;
        cursor[i] = base;
        base += deg[i];
    }
    if (t == 0) rowptr[N_NODES] = sums[1023];
}

// ---------------------------------------------------------------------------
// K3: scatter src ids into CSR slots (counting sort by dst)
// ---------------------------------------------------------------------------
__global__ __launch_bounds__(256) void csr_scatter_kernel(
    const int* __restrict__ src, const int* __restrict__ dst,
    int* __restrict__ cursor, int* __restrict__ csr_src)
{
    int e = blockIdx.x * blockDim.x + threadIdx.x;
    if (e >= N_EDGES) return;
    int pos = atomicAdd(&cursor[dst[e]], 1);
    csr_src[pos] = src[e];
}

// ---------------------------------------------------------------------------
// K4: per-dst-node fused dot + online softmax + weighted aggregate.
// 32 lanes per node (float4 each = 128 floats). Zero atomics, one store/lane.
// ---------------------------------------------------------------------------
__global__ __launch_bounds__(256) void node_aggregate_kernel(
    const float* __restrict__ emb,
    const int* __restrict__ rowptr,
    const int* __restrict__ csr_src,
    float* __restrict__ neigh)
{
    int node = blockIdx.x * 8 + (threadIdx.x >> 5);
    int lane = threadIdx.x & 31;
    if (node >= N_NODES) return;

    int beg = rowptr[node];
    int end = rowptr[node + 1];

    const float4 b = *((const float4*)(emb + (size_t)node * H_DIM) + lane);

    float m = -INFINITY;
    float denom = 0.f;
    float4 acc = {0.f, 0.f, 0.f, 0.f};

    for (int e = beg; e < end; ++e) {
        int s = csr_src[e];
        float4 a = *((const float4*)(emb + (size_t)s * H_DIM) + lane);
        float p = a.x * b.x + a.y * b.y + a.z * b.z + a.w * b.w;
        #pragma unroll
        for (int off = 16; off; off >>= 1)
            p += __shfl_xor(p, off);
        // online softmax update (uniform across the 32-lane group)
        float mn   = fmaxf(m, p);
        float corr = __expf(m - mn);   // first iter: exp(-inf)=0
        float w    = __expf(p - mn);
        denom = denom * corr + w;
        acc.x = acc.x * corr + a.x * w;
        acc.y = acc.y * corr + a.y * w;
        acc.z = acc.z * corr + a.z * w;
        acc.w = acc.w * corr + a.w * w;
        m = mn;
    }

    float inv = (end > beg) ? (1.0f / denom) : 0.f;
    float4 o = {acc.x * inv, acc.y * inv, acc.z * inv, acc.w * inv};
    *((float4*)(neigh + (size_t)node * H_DIM) + lane) = o;
}

// ---------------------------------------------------------------------------
// K5: h = neigh @ W (fp32, 32x128 block tile, 4x4 reg tile) + column stats
// ---------------------------------------------------------------------------
__global__ __launch_bounds__(256) void gemm_stats_kernel(
    const float* __restrict__ neigh,
    const float* __restrict__ W,
    float* __restrict__ h,
    float* __restrict__ colsum,
    float* __restrict__ colsq)
{
    __shared__ float Ws[128][128];   // 64 KB
    __shared__ float As[32][128];    // 16 KB

    int t  = threadIdx.x;
    int tx = t & 31;
    int ty = t >> 5;

    for (int i = t; i < 128 * 128; i += 256)
        Ws[i >> 7][i & 127] = W[i];

    float csum[4] = {0.f, 0.f, 0.f, 0.f};
    float csq[4]  = {0.f, 0.f, 0.f, 0.f};

    for (int r0 = blockIdx.x * 32; r0 < N_NODES; r0 += gridDim.x * 32) {
        __syncthreads();
        for (int i = t; i < 32 * 128; i += 256) {
            int r = i >> 7, k = i & 127;
            int gr = r0 + r;
            As[r][k] = (gr < N_NODES) ? neigh[(size_t)gr * H_DIM + k] : 0.f;
        }
        __syncthreads();

        float acc[4][4];
        #pragma unroll
        for (int i = 0; i < 4; ++i)
            #pragma unroll
            for (int j = 0; j < 4; ++j)
                acc[i][j] = 0.f;

        #pragma unroll 8
        for (int k = 0; k < 128; ++k) {
            float4 w = *(const float4*)(&Ws[k][tx * 4]);
            #pragma unroll
            for (int i = 0; i < 4; ++i) {
                float a = As[ty * 4 + i][k];
                acc[i][0] += a * w.x;
                acc[i][1] += a * w.y;
                acc[i][2] += a * w.z;
                acc[i][3] += a * w.w;
            }
        }

        #pragma unroll
        for (int i = 0; i < 4; ++i) {
            int gr = r0 + ty * 4 + i;
            if (gr < N_NODES) {
                float4 out;
                out.x = acc[i][0]; out.y = acc[i][1];
                out.z = acc[i][2]; out.w = acc[i][3];
                *(float4*)(h + (size_t)gr * H_DIM + tx * 4) = out;
                #pragma unroll
                for (int j = 0; j < 4; ++j) {
                    csum[j] += acc[i][j];
                    csq[j]  += acc[i][j] * acc[i][j];
                }
            }
        }
    }

    #pragma unroll
    for (int j = 0; j < 4; ++j) {
        unsafeAtomicAdd(colsum + tx * 4 + j, csum[j]);
        unsafeAtomicAdd(colsq  + tx * 4 + j, csq[j]);
    }
}

// ---------------------------------------------------------------------------
// K6: fold BN stats into per-column scale/shift
// ---------------------------------------------------------------------------
__global__ void bn_stats_kernel(
    const float* __restrict__ colsum,
    const float* __restrict__ colsq,
    const float* __restrict__ gamma,
    const float* __restrict__ beta,
    float* __restrict__ scale,
    float* __restrict__ shift)
{
    int c = threadIdx.x;
    const float invN = 1.0f / (float)N_NODES;
    float mu  = colsum[c] * invN;
    float var = colsq[c] * invN - mu * mu;
    float sc  = gamma[c] * rsqrtf(var + BN_EPS);
    scale[c] = sc;
    shift[c] = beta[c] - mu * sc;
}

// ---------------------------------------------------------------------------
// K7: out = tanh(h*scale + shift), in place
// ---------------------------------------------------------------------------
__global__ __launch_bounds__(256) void bn_tanh_kernel(
    float* __restrict__ h,
    const float* __restrict__ scale,
    const float* __restrict__ shift)
{
    size_t i = (size_t)blockIdx.x * blockDim.x + threadIdx.x;
    size_t idx4 = i * 4;
    if (idx4 >= (size_t)N_NODES * H_DIM) return;
    int c = (int)(idx4 & (H_DIM - 1));
    float4 v = *(float4*)(h + idx4);
    v.x = tanhf(v.x * scale[c + 0] + shift[c + 0]);
    v.y = tanhf(v.y * scale[c + 1] + shift[c + 1]);
    v.z = tanhf(v.z * scale[c + 2] + shift[c + 2]);
    v.w = tanhf(v.w * scale[c + 3] + shift[c + 3]);
    *(float4*)(h + idx4) = v;
}

// ---------------------------------------------------------------------------
extern "C" void kernel_launch(void* const* d_in, const int* in_sizes, int n_in,
                              void* d_out, int out_size, void* d_ws, size_t ws_size,
                              hipStream_t stream)
{
    const float* ent_emb = (const float*)d_in[0];
    const float* neigh_w = (const float*)d_in[1];
    const float* gamma   = (const float*)d_in[2];
    const float* beta    = (const float*)d_in[3];
    const int*   src     = (const int*)d_in[4];
    const int*   dst     = (const int*)d_in[5];
    float* out = (float*)d_out;

    char* ws = (char*)d_ws;
    float* neigh   = (float*)ws;                                    // 25.6 MB
    int*   deg     = (int*)(ws + (size_t)N_NODES * H_DIM * 4);      // 50000
    int*   rowptr  = deg + N_NODES;                                 // 50001
    int*   cursor  = rowptr + N_NODES + 1;                          // 50000
    int*   csr_src = cursor + N_NODES;                              // 500000
    float* colsum  = (float*)(csr_src + N_EDGES);
    float* colsq   = colsum + H_DIM;
    float* scale   = colsq + H_DIM;
    float* shift   = scale + H_DIM;

    hipMemsetAsync(deg, 0, N_NODES * sizeof(int), stream);
    hipMemsetAsync(colsum, 0, 2 * H_DIM * sizeof(float), stream);

    // CSR build (counting sort by dst)
    hist_kernel<<<(N_EDGES + 255) / 256, 256, 0, stream>>>(dst, deg);
    scan_kernel<<<1, 1024, 0, stream>>>(deg, rowptr, cursor);
    csr_scatter_kernel<<<(N_EDGES + 255) / 256, 256, 0, stream>>>(src, dst, cursor, csr_src);

    // fused dot + online softmax + aggregate (one store per lane, no atomics)
    node_aggregate_kernel<<<(N_NODES + 7) / 8, 256, 0, stream>>>(
        ent_emb, rowptr, csr_src, neigh);

    // h = neigh @ W + stats, then BN + tanh
    gemm_stats_kernel<<<512, 256, 0, stream>>>(neigh, neigh_w, out, colsum, colsq);
    bn_stats_kernel<<<1, 128, 0, stream>>>(colsum, colsq, gamma, beta, scale, shift);
    {
        size_t total4 = (size_t)N_NODES * H_DIM / 4;
        int blocks = (int)((total4 + 255) / 256);
        bn_tanh_kernel<<<blocks, 256, 0, stream>>>(out, scale, shift);
    }
}

// Round 4
// 299.542 us; speedup vs baseline: 4.5567x; 2.4342x over previous
//
#include <hip/hip_runtime.h>
#include <hip/hip_bf16.h>
#include <math.h>

#define N_NODES 50000
#define N_EDGES 500000
#define H_DIM   128
#define BN_EPS  1e-5f
#define GEMM_GRID 512

// ---------------------------------------------------------------------------
// K1: histogram of dst -> deg[]
// ---------------------------------------------------------------------------
__global__ __launch_bounds__(256) void hist_kernel(
    const int* __restrict__ dst, int* __restrict__ deg)
{
    int e = blockIdx.x * blockDim.x + threadIdx.x;
    if (e < N_EDGES) atomicAdd(&deg[dst[e]], 1);
}

// ---------------------------------------------------------------------------
// K2: exclusive prefix sum of deg -> rowptr[0..N], cursor (copy). One block.
// ---------------------------------------------------------------------------
__global__ __launch_bounds__(1024) void scan_kernel(
    const int* __restrict__ deg, int* __restrict__ rowptr, int* __restrict__ cursor)
{
    __shared__ int sums[1024];
    int t = threadIdx.x;
    const int CH = (N_NODES + 1023) / 1024;   // 49
    int beg = t * CH;
    int end = min(beg + CH, N_NODES);
    int s = 0;
    for (int i = beg; i < end; ++i) s += deg[i];
    sums[t] = s;
    __syncthreads();
    for (int off = 1; off < 1024; off <<= 1) {
        int v = (t >= off) ? sums[t - off] : 0;
        __syncthreads();
        sums[t] += v;
        __syncthreads();
    }
    int base = (t == 0) ? 0 : sums[t - 1];    // exclusive prefix
    for (int i = beg; i < end; ++i) {
        rowptr[i] = base;
        cursor[i] = base;
        base += deg[i];
    }
    if (t == 0) rowptr[N_NODES] = sums[1023];
}

// ---------------------------------------------------------------------------
// K3: scatter src ids into CSR slots (counting sort by dst)
// ---------------------------------------------------------------------------
__global__ __launch_bounds__(256) void csr_scatter_kernel(
    const int* __restrict__ src, const int* __restrict__ dst,
    int* __restrict__ cursor, int* __restrict__ csr_src)
{
    int e = blockIdx.x * blockDim.x + threadIdx.x;
    if (e >= N_EDGES) return;
    int pos = atomicAdd(&cursor[dst[e]], 1);
    csr_src[pos] = src[e];
}

// ---------------------------------------------------------------------------
// K4: per-dst-node fused dot + online softmax + weighted aggregate.
// 32 lanes per node (float4 each = 128 floats). Zero atomics, one store/lane.
// ---------------------------------------------------------------------------
__global__ __launch_bounds__(256) void node_aggregate_kernel(
    const float* __restrict__ emb,
    const int* __restrict__ rowptr,
    const int* __restrict__ csr_src,
    float* __restrict__ neigh)
{
    int node = blockIdx.x * 8 + (threadIdx.x >> 5);
    int lane = threadIdx.x & 31;
    if (node >= N_NODES) return;

    int beg = rowptr[node];
    int end = rowptr[node + 1];

    const float4 b = *((const float4*)(emb + (size_t)node * H_DIM) + lane);

    float m = -INFINITY;
    float denom = 0.f;
    float4 acc = {0.f, 0.f, 0.f, 0.f};

    for (int e = beg; e < end; ++e) {
        int s = csr_src[e];
        float4 a = *((const float4*)(emb + (size_t)s * H_DIM) + lane);
        float p = a.x * b.x + a.y * b.y + a.z * b.z + a.w * b.w;
        #pragma unroll
        for (int off = 16; off; off >>= 1)
            p += __shfl_xor(p, off);
        float mn   = fmaxf(m, p);
        float corr = __expf(m - mn);   // first iter: exp(-inf)=0
        float w    = __expf(p - mn);
        denom = denom * corr + w;
        acc.x = acc.x * corr + a.x * w;
        acc.y = acc.y * corr + a.y * w;
        acc.z = acc.z * corr + a.z * w;
        acc.w = acc.w * corr + a.w * w;
        m = mn;
    }

    float inv = (end > beg) ? (1.0f / denom) : 0.f;
    float4 o = {acc.x * inv, acc.y * inv, acc.z * inv, acc.w * inv};
    *((float4*)(neigh + (size_t)node * H_DIM) + lane) = o;
}

// ---------------------------------------------------------------------------
// K5: h = neigh @ W (fp32, 32x128 block tile, 4x4 reg tile) + column partials.
// Column sum/sumsq reduced across the block in LDS (reusing As) and written as
// ONE plain store per thread -> partial[block][256]. No atomics (the round-3
// 1M-atomics-to-16-lines tail was 97% of this kernel's time).
// partial value layout: v = tx*8 + j, j in 0..3 = csum cols 4tx+j,
//                                     j in 4..7 = csq  cols 4tx+(j-4).
// ---------------------------------------------------------------------------
__global__ __launch_bounds__(256) void gemm_stats_kernel(
    const float* __restrict__ neigh,
    const float* __restrict__ W,
    float* __restrict__ h,
    float* __restrict__ partial)
{
    __shared__ float Ws[128][128];   // 64 KB
    __shared__ float As[32][128];    // 16 KB (reused for the final reduction)

    int t  = threadIdx.x;
    int tx = t & 31;
    int ty = t >> 5;

    for (int i = t; i < 128 * 128; i += 256)
        Ws[i >> 7][i & 127] = W[i];

    float csum[4] = {0.f, 0.f, 0.f, 0.f};
    float csq[4]  = {0.f, 0.f, 0.f, 0.f};

    for (int r0 = blockIdx.x * 32; r0 < N_NODES; r0 += gridDim.x * 32) {
        __syncthreads();
        for (int i = t; i < 32 * 128; i += 256) {
            int r = i >> 7, k = i & 127;
            int gr = r0 + r;
            As[r][k] = (gr < N_NODES) ? neigh[(size_t)gr * H_DIM + k] : 0.f;
        }
        __syncthreads();

        float acc[4][4];
        #pragma unroll
        for (int i = 0; i < 4; ++i)
            #pragma unroll
            for (int j = 0; j < 4; ++j)
                acc[i][j] = 0.f;

        #pragma unroll 8
        for (int k = 0; k < 128; ++k) {
            float4 w = *(const float4*)(&Ws[k][tx * 4]);
            #pragma unroll
            for (int i = 0; i < 4; ++i) {
                float a = As[ty * 4 + i][k];
                acc[i][0] += a * w.x;
                acc[i][1] += a * w.y;
                acc[i][2] += a * w.z;
                acc[i][3] += a * w.w;
            }
        }

        #pragma unroll
        for (int i = 0; i < 4; ++i) {
            int gr = r0 + ty * 4 + i;
            if (gr < N_NODES) {
                float4 out;
                out.x = acc[i][0]; out.y = acc[i][1];
                out.z = acc[i][2]; out.w = acc[i][3];
                *(float4*)(h + (size_t)gr * H_DIM + tx * 4) = out;
                #pragma unroll
                for (int j = 0; j < 4; ++j) {
                    csum[j] += acc[i][j];
                    csq[j]  += acc[i][j] * acc[i][j];
                }
            }
        }
    }

    // ---- block-level reduction of csum/csq across ty, zero atomics ----
    __syncthreads();
    float* red = &As[0][0];          // 2048 floats needed, 4096 available
    #pragma unroll
    for (int j = 0; j < 4; ++j) {
        red[(tx * 8 + j) * 8 + ty]       = csum[j];
        red[(tx * 8 + 4 + j) * 8 + ty]   = csq[j];
    }
    __syncthreads();
    float s = 0.f;
    #pragma unroll
    for (int q = 0; q < 8; ++q)
        s += red[t * 8 + q];
    partial[(size_t)blockIdx.x * 256 + t] = s;   // coalesced plain store
}

// ---------------------------------------------------------------------------
// K6: sum partials, fold BN stats into per-column scale/shift. One block.
// ---------------------------------------------------------------------------
__global__ __launch_bounds__(256) void bn_stats_kernel(
    const float* __restrict__ partial,
    const float* __restrict__ gamma,
    const float* __restrict__ beta,
    float* __restrict__ scale,
    float* __restrict__ shift)
{
    __shared__ float tot[256];
    int v = threadIdx.x;
    float s = 0.f;
    #pragma unroll 8
    for (int b = 0; b < GEMM_GRID; ++b)
        s += partial[(size_t)b * 256 + v];     // coalesced, L2-resident
    tot[v] = s;
    __syncthreads();
    if (v < 128) {
        int c = v;
        int base = (c >> 2) * 8 + (c & 3);
        float cs = tot[base];
        float cq = tot[base + 4];
        const float invN = 1.0f / (float)N_NODES;
        float mu  = cs * invN;
        float var = cq * invN - mu * mu;       // biased, matches jnp.var
        float sc  = gamma[c] * rsqrtf(var + BN_EPS);
        scale[c] = sc;
        shift[c] = beta[c] - mu * sc;
    }
}

// ---------------------------------------------------------------------------
// K7: out = tanh(h*scale + shift), in place
// ---------------------------------------------------------------------------
__global__ __launch_bounds__(256) void bn_tanh_kernel(
    float* __restrict__ h,
    const float* __restrict__ scale,
    const float* __restrict__ shift)
{
    size_t i = (size_t)blockIdx.x * blockDim.x + threadIdx.x;
    size_t idx4 = i * 4;
    if (idx4 >= (size_t)N_NODES * H_DIM) return;
    int c = (int)(idx4 & (H_DIM - 1));
    float4 v = *(float4*)(h + idx4);
    v.x = tanhf(v.x * scale[c + 0] + shift[c + 0]);
    v.y = tanhf(v.y * scale[c + 1] + shift[c + 1]);
    v.z = tanhf(v.z * scale[c + 2] + shift[c + 2]);
    v.w = tanhf(v.w * scale[c + 3] + shift[c + 3]);
    *(float4*)(h + idx4) = v;
}

// ---------------------------------------------------------------------------
extern "C" void kernel_launch(void* const* d_in, const int* in_sizes, int n_in,
                              void* d_out, int out_size, void* d_ws, size_t ws_size,
                              hipStream_t stream)
{
    const float* ent_emb = (const float*)d_in[0];
    const float* neigh_w = (const float*)d_in[1];
    const float* gamma   = (const float*)d_in[2];
    const float* beta    = (const float*)d_in[3];
    const int*   src     = (const int*)d_in[4];
    const int*   dst     = (const int*)d_in[5];
    float* out = (float*)d_out;

    char* ws = (char*)d_ws;
    float* neigh   = (float*)ws;                                    // 25.6 MB
    int*   deg     = (int*)(ws + (size_t)N_NODES * H_DIM * 4);      // 50000
    int*   rowptr  = deg + N_NODES;                                 // 50001
    int*   cursor  = rowptr + N_NODES + 1;                          // 50000
    int*   csr_src = cursor + N_NODES;                              // 500000
    float* partial = (float*)(csr_src + N_EDGES);                   // 512*256
    float* scale   = partial + (size_t)GEMM_GRID * 256;
    float* shift   = scale + H_DIM;

    hipMemsetAsync(deg, 0, N_NODES * sizeof(int), stream);

    // CSR build (counting sort by dst)
    hist_kernel<<<(N_EDGES + 255) / 256, 256, 0, stream>>>(dst, deg);
    scan_kernel<<<1, 1024, 0, stream>>>(deg, rowptr, cursor);
    csr_scatter_kernel<<<(N_EDGES + 255) / 256, 256, 0, stream>>>(src, dst, cursor, csr_src);

    // fused dot + online softmax + aggregate (one store per lane, no atomics)
    node_aggregate_kernel<<<(N_NODES + 7) / 8, 256, 0, stream>>>(
        ent_emb, rowptr, csr_src, neigh);

    // h = neigh @ W + column partials, then BN + tanh
    gemm_stats_kernel<<<GEMM_GRID, 256, 0, stream>>>(neigh, neigh_w, out, partial);
    bn_stats_kernel<<<1, 256, 0, stream>>>(partial, gamma, beta, scale, shift);
    {
        size_t total4 = (size_t)N_NODES * H_DIM / 4;
        int blocks = (int)((total4 + 255) / 256);
        bn_tanh_kernel<<<blocks, 256, 0, stream>>>(out, scale, shift);
    }
}

// Round 5
// 200.242 us; speedup vs baseline: 6.8164x; 1.4959x over previous
//
#include <hip/hip_runtime.h>
#include <hip/hip_bf16.h>
#include <math.h>

#define N_NODES 50000
#define N_EDGES 500000
#define H_DIM   128
#define BN_EPS  1e-5f
#define GEMM_GRID 512
#define SCAN_NBLK ((N_NODES + 255) / 256)   // 196

// ---------------------------------------------------------------------------
// K1: histogram of dst -> deg[]
// ---------------------------------------------------------------------------
__global__ __launch_bounds__(256) void hist_kernel(
    const int* __restrict__ dst, int* __restrict__ deg)
{
    int e = blockIdx.x * blockDim.x + threadIdx.x;
    if (e < N_EDGES) atomicAdd(&deg[dst[e]], 1);
}

// ---------------------------------------------------------------------------
// K2a: per-block sums of deg (196 blocks x 256)
// ---------------------------------------------------------------------------
__global__ __launch_bounds__(256) void scan_partial_kernel(
    const int* __restrict__ deg, int* __restrict__ blocksum)
{
    __shared__ int red[256];
    int t = threadIdx.x;
    int i = blockIdx.x * 256 + t;
    red[t] = (i < N_NODES) ? deg[i] : 0;
    __syncthreads();
    #pragma unroll
    for (int off = 128; off; off >>= 1) {
        if (t < off) red[t] += red[t + off];
        __syncthreads();
    }
    if (t == 0) blocksum[blockIdx.x] = red[0];
}

// ---------------------------------------------------------------------------
// K2b: exclusive scan of the 196 block sums (one 256-thread block)
// ---------------------------------------------------------------------------
__global__ __launch_bounds__(256) void scan_blocksums_kernel(
    const int* __restrict__ blocksum, int* __restrict__ blockoff)
{
    __shared__ int s[256];
    int t = threadIdx.x;
    s[t] = (t < SCAN_NBLK) ? blocksum[t] : 0;
    __syncthreads();
    for (int off = 1; off < 256; off <<= 1) {
        int v = (t >= off) ? s[t - off] : 0;
        __syncthreads();
        s[t] += v;
        __syncthreads();
    }
    if (t < SCAN_NBLK) blockoff[t] = (t == 0) ? 0 : s[t - 1];
}

// ---------------------------------------------------------------------------
// K2c: in-block exclusive scan + block offset -> rowptr, cursor
// ---------------------------------------------------------------------------
__global__ __launch_bounds__(256) void scan_final_kernel(
    const int* __restrict__ deg, const int* __restrict__ blockoff,
    int* __restrict__ rowptr, int* __restrict__ cursor)
{
    __shared__ int s[256];
    int t = threadIdx.x;
    int i = blockIdx.x * 256 + t;
    int v = (i < N_NODES) ? deg[i] : 0;
    s[t] = v;
    __syncthreads();
    for (int off = 1; off < 256; off <<= 1) {
        int u = (t >= off) ? s[t - off] : 0;
        __syncthreads();
        s[t] += u;
        __syncthreads();
    }
    int excl = s[t] - v + blockoff[blockIdx.x];
    if (i < N_NODES) {
        rowptr[i] = excl;
        cursor[i] = excl;
        if (i == N_NODES - 1) rowptr[N_NODES] = excl + v;
    }
}

// ---------------------------------------------------------------------------
// K3: scatter src ids into CSR slots (counting sort by dst)
// ---------------------------------------------------------------------------
__global__ __launch_bounds__(256) void csr_scatter_kernel(
    const int* __restrict__ src, const int* __restrict__ dst,
    int* __restrict__ cursor, int* __restrict__ csr_src)
{
    int e = blockIdx.x * blockDim.x + threadIdx.x;
    if (e >= N_EDGES) return;
    int pos = atomicAdd(&cursor[dst[e]], 1);
    csr_src[pos] = src[e];
}

// ---------------------------------------------------------------------------
// K4: per-dst-node fused dot + online softmax + weighted aggregate.
// 32 lanes per node (float4 each = 128 floats). Zero atomics, one store/lane.
// ---------------------------------------------------------------------------
__global__ __launch_bounds__(256) void node_aggregate_kernel(
    const float* __restrict__ emb,
    const int* __restrict__ rowptr,
    const int* __restrict__ csr_src,
    float* __restrict__ neigh)
{
    int node = blockIdx.x * 8 + (threadIdx.x >> 5);
    int lane = threadIdx.x & 31;
    if (node >= N_NODES) return;

    int beg = rowptr[node];
    int end = rowptr[node + 1];

    const float4 b = *((const float4*)(emb + (size_t)node * H_DIM) + lane);

    float m = -INFINITY;
    float denom = 0.f;
    float4 acc = {0.f, 0.f, 0.f, 0.f};

    for (int e = beg; e < end; ++e) {
        int s = csr_src[e];
        float4 a = *((const float4*)(emb + (size_t)s * H_DIM) + lane);
        float p = a.x * b.x + a.y * b.y + a.z * b.z + a.w * b.w;
        #pragma unroll
        for (int off = 16; off; off >>= 1)
            p += __shfl_xor(p, off);
        float mn   = fmaxf(m, p);
        float corr = __expf(m - mn);   // first iter: exp(-inf)=0
        float w    = __expf(p - mn);
        denom = denom * corr + w;
        acc.x = acc.x * corr + a.x * w;
        acc.y = acc.y * corr + a.y * w;
        acc.z = acc.z * corr + a.z * w;
        acc.w = acc.w * corr + a.w * w;
        m = mn;
    }

    float inv = (end > beg) ? (1.0f / denom) : 0.f;
    float4 o = {acc.x * inv, acc.y * inv, acc.z * inv, acc.w * inv};
    *((float4*)(neigh + (size_t)node * H_DIM) + lane) = o;
}

// ---------------------------------------------------------------------------
// K5: h = neigh @ W (fp32, 32x128 block tile, 4x4 reg tile) + column partials.
// Block-level LDS reduction of sum/sumsq, one plain store/thread. No atomics.
// ---------------------------------------------------------------------------
__global__ __launch_bounds__(256) void gemm_stats_kernel(
    const float* __restrict__ neigh,
    const float* __restrict__ W,
    float* __restrict__ h,
    float* __restrict__ partial)
{
    __shared__ float Ws[128][128];   // 64 KB
    __shared__ float As[32][128];    // 16 KB (reused for the final reduction)

    int t  = threadIdx.x;
    int tx = t & 31;
    int ty = t >> 5;

    for (int i = t; i < 128 * 128; i += 256)
        Ws[i >> 7][i & 127] = W[i];

    float csum[4] = {0.f, 0.f, 0.f, 0.f};
    float csq[4]  = {0.f, 0.f, 0.f, 0.f};

    for (int r0 = blockIdx.x * 32; r0 < N_NODES; r0 += gridDim.x * 32) {
        __syncthreads();
        for (int i = t; i < 32 * 128; i += 256) {
            int r = i >> 7, k = i & 127;
            int gr = r0 + r;
            As[r][k] = (gr < N_NODES) ? neigh[(size_t)gr * H_DIM + k] : 0.f;
        }
        __syncthreads();

        float acc[4][4];
        #pragma unroll
        for (int i = 0; i < 4; ++i)
            #pragma unroll
            for (int j = 0; j < 4; ++j)
                acc[i][j] = 0.f;

        #pragma unroll 8
        for (int k = 0; k < 128; ++k) {
            float4 w = *(const float4*)(&Ws[k][tx * 4]);
            #pragma unroll
            for (int i = 0; i < 4; ++i) {
                float a = As[ty * 4 + i][k];
                acc[i][0] += a * w.x;
                acc[i][1] += a * w.y;
                acc[i][2] += a * w.z;
                acc[i][3] += a * w.w;
            }
        }

        #pragma unroll
        for (int i = 0; i < 4; ++i) {
            int gr = r0 + ty * 4 + i;
            if (gr < N_NODES) {
                float4 out;
                out.x = acc[i][0]; out.y = acc[i][1];
                out.z = acc[i][2]; out.w = acc[i][3];
                *(float4*)(h + (size_t)gr * H_DIM + tx * 4) = out;
                #pragma unroll
                for (int j = 0; j < 4; ++j) {
                    csum[j] += acc[i][j];
                    csq[j]  += acc[i][j] * acc[i][j];
                }
            }
        }
    }

    // ---- block-level reduction of csum/csq across ty, zero atomics ----
    __syncthreads();
    float* red = &As[0][0];          // 2048 floats needed, 4096 available
    #pragma unroll
    for (int j = 0; j < 4; ++j) {
        red[(tx * 8 + j) * 8 + ty]       = csum[j];
        red[(tx * 8 + 4 + j) * 8 + ty]   = csq[j];
    }
    __syncthreads();
    float s = 0.f;
    #pragma unroll
    for (int q = 0; q < 8; ++q)
        s += red[t * 8 + q];
    partial[(size_t)blockIdx.x * 256 + t] = s;   // coalesced plain store
}

// ---------------------------------------------------------------------------
// K6: sum partials, fold BN stats into per-column scale/shift. One block.
// ---------------------------------------------------------------------------
__global__ __launch_bounds__(256) void bn_stats_kernel(
    const float* __restrict__ partial,
    const float* __restrict__ gamma,
    const float* __restrict__ beta,
    float* __restrict__ scale,
    float* __restrict__ shift)
{
    __shared__ float tot[256];
    int v = threadIdx.x;
    float s = 0.f;
    #pragma unroll 8
    for (int b = 0; b < GEMM_GRID; ++b)
        s += partial[(size_t)b * 256 + v];     // coalesced, L2-resident
    tot[v] = s;
    __syncthreads();
    if (v < 128) {
        int c = v;
        int base = (c >> 2) * 8 + (c & 3);
        float cs = tot[base];
        float cq = tot[base + 4];
        const float invN = 1.0f / (float)N_NODES;
        float mu  = cs * invN;
        float var = cq * invN - mu * mu;       // biased, matches jnp.var
        float sc  = gamma[c] * rsqrtf(var + BN_EPS);
        scale[c] = sc;
        shift[c] = beta[c] - mu * sc;
    }
}

// ---------------------------------------------------------------------------
// K7: out = tanh(h*scale + shift), in place
// ---------------------------------------------------------------------------
__global__ __launch_bounds__(256) void bn_tanh_kernel(
    float* __restrict__ h,
    const float* __restrict__ scale,
    const float* __restrict__ shift)
{
    size_t i = (size_t)blockIdx.x * blockDim.x + threadIdx.x;
    size_t idx4 = i * 4;
    if (idx4 >= (size_t)N_NODES * H_DIM) return;
    int c = (int)(idx4 & (H_DIM - 1));
    float4 v = *(float4*)(h + idx4);
    v.x = tanhf(v.x * scale[c + 0] + shift[c + 0]);
    v.y = tanhf(v.y * scale[c + 1] + shift[c + 1]);
    v.z = tanhf(v.z * scale[c + 2] + shift[c + 2]);
    v.w = tanhf(v.w * scale[c + 3] + shift[c + 3]);
    *(float4*)(h + idx4) = v;
}

// ---------------------------------------------------------------------------
extern "C" void kernel_launch(void* const* d_in, const int* in_sizes, int n_in,
                              void* d_out, int out_size, void* d_ws, size_t ws_size,
                              hipStream_t stream)
{
    const float* ent_emb = (const float*)d_in[0];
    const float* neigh_w = (const float*)d_in[1];
    const float* gamma   = (const float*)d_in[2];
    const float* beta    = (const float*)d_in[3];
    const int*   src     = (const int*)d_in[4];
    const int*   dst     = (const int*)d_in[5];
    float* out = (float*)d_out;

    char* ws = (char*)d_ws;
    float* neigh    = (float*)ws;                                    // 25.6 MB
    int*   deg      = (int*)(ws + (size_t)N_NODES * H_DIM * 4);      // 50000
    int*   rowptr   = deg + N_NODES;                                 // 50001
    int*   cursor   = rowptr + N_NODES + 1;                          // 50000
    int*   csr_src  = cursor + N_NODES;                              // 500000
    int*   blocksum = csr_src + N_EDGES;                             // 196
    int*   blockoff = blocksum + SCAN_NBLK;                          // 196
    float* partial  = (float*)(blockoff + SCAN_NBLK);                // 512*256
    float* scale    = partial + (size_t)GEMM_GRID * 256;
    float* shift    = scale + H_DIM;

    hipMemsetAsync(deg, 0, N_NODES * sizeof(int), stream);

    // CSR build (counting sort by dst); hierarchical 3-kernel scan
    hist_kernel<<<(N_EDGES + 255) / 256, 256, 0, stream>>>(dst, deg);
    scan_partial_kernel<<<SCAN_NBLK, 256, 0, stream>>>(deg, blocksum);
    scan_blocksums_kernel<<<1, 256, 0, stream>>>(blocksum, blockoff);
    scan_final_kernel<<<SCAN_NBLK, 256, 0, stream>>>(deg, blockoff, rowptr, cursor);
    csr_scatter_kernel<<<(N_EDGES + 255) / 256, 256, 0, stream>>>(src, dst, cursor, csr_src);

    // fused dot + online softmax + aggregate (one store per lane, no atomics)
    node_aggregate_kernel<<<(N_NODES + 7) / 8, 256, 0, stream>>>(
        ent_emb, rowptr, csr_src, neigh);

    // h = neigh @ W + column partials, then BN + tanh
    gemm_stats_kernel<<<GEMM_GRID, 256, 0, stream>>>(neigh, neigh_w, out, partial);
    bn_stats_kernel<<<1, 256, 0, stream>>>(partial, gamma, beta, scale, shift);
    {
        size_t total4 = (size_t)N_NODES * H_DIM / 4;
        int blocks = (int)((total4 + 255) / 256);
        bn_tanh_kernel<<<blocks, 256, 0, stream>>>(out, scale, shift);
    }
}

// Round 6
// 189.526 us; speedup vs baseline: 7.2018x; 1.0565x over previous
//
#include <hip/hip_runtime.h>
#include <hip/hip_bf16.h>
#include <math.h>

#define N_NODES 50000
#define N_EDGES 500000
#define H_DIM   128
#define BN_EPS  1e-5f
#define GEMM_GRID 512
#define SCAN_NBLK ((N_NODES + 255) / 256)   // 196

// ---------------------------------------------------------------------------
// K1: histogram of dst -> deg[]
// ---------------------------------------------------------------------------
__global__ __launch_bounds__(256) void hist_kernel(
    const int* __restrict__ dst, int* __restrict__ deg)
{
    int e = blockIdx.x * blockDim.x + threadIdx.x;
    if (e < N_EDGES) atomicAdd(&deg[dst[e]], 1);
}

// ---------------------------------------------------------------------------
// K2a: per-block sums of deg (196 blocks x 256)
// ---------------------------------------------------------------------------
__global__ __launch_bounds__(256) void scan_partial_kernel(
    const int* __restrict__ deg, int* __restrict__ blocksum)
{
    __shared__ int red[256];
    int t = threadIdx.x;
    int i = blockIdx.x * 256 + t;
    red[t] = (i < N_NODES) ? deg[i] : 0;
    __syncthreads();
    #pragma unroll
    for (int off = 128; off; off >>= 1) {
        if (t < off) red[t] += red[t + off];
        __syncthreads();
    }
    if (t == 0) blocksum[blockIdx.x] = red[0];
}

// ---------------------------------------------------------------------------
// K2b: exclusive scan of the 196 block sums (one 256-thread block)
// ---------------------------------------------------------------------------
__global__ __launch_bounds__(256) void scan_blocksums_kernel(
    const int* __restrict__ blocksum, int* __restrict__ blockoff)
{
    __shared__ int s[256];
    int t = threadIdx.x;
    s[t] = (t < SCAN_NBLK) ? blocksum[t] : 0;
    __syncthreads();
    for (int off = 1; off < 256; off <<= 1) {
        int v = (t >= off) ? s[t - off] : 0;
        __syncthreads();
        s[t] += v;
        __syncthreads();
    }
    if (t < SCAN_NBLK) blockoff[t] = (t == 0) ? 0 : s[t - 1];
}

// ---------------------------------------------------------------------------
// K2c: in-block exclusive scan + block offset -> rowptr, cursor
// ---------------------------------------------------------------------------
__global__ __launch_bounds__(256) void scan_final_kernel(
    const int* __restrict__ deg, const int* __restrict__ blockoff,
    int* __restrict__ rowptr, int* __restrict__ cursor)
{
    __shared__ int s[256];
    int t = threadIdx.x;
    int i = blockIdx.x * 256 + t;
    int v = (i < N_NODES) ? deg[i] : 0;
    s[t] = v;
    __syncthreads();
    for (int off = 1; off < 256; off <<= 1) {
        int u = (t >= off) ? s[t - off] : 0;
        __syncthreads();
        s[t] += u;
        __syncthreads();
    }
    int excl = s[t] - v + blockoff[blockIdx.x];
    if (i < N_NODES) {
        rowptr[i] = excl;
        cursor[i] = excl;
        if (i == N_NODES - 1) rowptr[N_NODES] = excl + v;
    }
}

// ---------------------------------------------------------------------------
// K3: scatter src ids into CSR slots (counting sort by dst)
// ---------------------------------------------------------------------------
__global__ __launch_bounds__(256) void csr_scatter_kernel(
    const int* __restrict__ src, const int* __restrict__ dst,
    int* __restrict__ cursor, int* __restrict__ csr_src)
{
    int e = blockIdx.x * blockDim.x + threadIdx.x;
    if (e >= N_EDGES) return;
    int pos = atomicAdd(&cursor[dst[e]], 1);
    csr_src[pos] = src[e];
}

// ---------------------------------------------------------------------------
// K4: per-dst-node fused dot + online softmax + weighted aggregate.
// 32 lanes per node. 4-way edge unroll: 4 outstanding gathers, 4 interleaved
// shfl-reduce chains, one batched online-softmax rescale per 4 edges.
// Zero atomics, one float4 store per lane.
// ---------------------------------------------------------------------------
__global__ __launch_bounds__(256) void node_aggregate_kernel(
    const float* __restrict__ emb,
    const int* __restrict__ rowptr,
    const int* __restrict__ csr_src,
    float* __restrict__ neigh)
{
    int node = blockIdx.x * 8 + (threadIdx.x >> 5);
    int lane = threadIdx.x & 31;
    if (node >= N_NODES) return;

    int beg = rowptr[node];
    int end = rowptr[node + 1];

    const float4 b = *((const float4*)(emb + (size_t)node * H_DIM) + lane);

    float m = -INFINITY;
    float denom = 0.f;
    float4 acc = {0.f, 0.f, 0.f, 0.f};

    int e = beg;
    for (; e + 4 <= end; e += 4) {
        int s0 = csr_src[e + 0];
        int s1 = csr_src[e + 1];
        int s2 = csr_src[e + 2];
        int s3 = csr_src[e + 3];
        float4 a0 = *((const float4*)(emb + (size_t)s0 * H_DIM) + lane);
        float4 a1 = *((const float4*)(emb + (size_t)s1 * H_DIM) + lane);
        float4 a2 = *((const float4*)(emb + (size_t)s2 * H_DIM) + lane);
        float4 a3 = *((const float4*)(emb + (size_t)s3 * H_DIM) + lane);
        float p0 = a0.x * b.x + a0.y * b.y + a0.z * b.z + a0.w * b.w;
        float p1 = a1.x * b.x + a1.y * b.y + a1.z * b.z + a1.w * b.w;
        float p2 = a2.x * b.x + a2.y * b.y + a2.z * b.z + a2.w * b.w;
        float p3 = a3.x * b.x + a3.y * b.y + a3.z * b.z + a3.w * b.w;
        #pragma unroll
        for (int off = 16; off; off >>= 1) {
            p0 += __shfl_xor(p0, off);
            p1 += __shfl_xor(p1, off);
            p2 += __shfl_xor(p2, off);
            p3 += __shfl_xor(p3, off);
        }
        // batched online softmax update (== 4 sequential updates)
        float mn = fmaxf(fmaxf(fmaxf(p0, p1), fmaxf(p2, p3)), m);
        float corr = __expf(m - mn);          // first iter: exp(-inf)=0
        float w0 = __expf(p0 - mn);
        float w1 = __expf(p1 - mn);
        float w2 = __expf(p2 - mn);
        float w3 = __expf(p3 - mn);
        denom = denom * corr + w0 + w1 + w2 + w3;
        acc.x = acc.x * corr + a0.x * w0 + a1.x * w1 + a2.x * w2 + a3.x * w3;
        acc.y = acc.y * corr + a0.y * w0 + a1.y * w1 + a2.y * w2 + a3.y * w3;
        acc.z = acc.z * corr + a0.z * w0 + a1.z * w1 + a2.z * w2 + a3.z * w3;
        acc.w = acc.w * corr + a0.w * w0 + a1.w * w1 + a2.w * w2 + a3.w * w3;
        m = mn;
    }
    for (; e < end; ++e) {
        int s = csr_src[e];
        float4 a = *((const float4*)(emb + (size_t)s * H_DIM) + lane);
        float p = a.x * b.x + a.y * b.y + a.z * b.z + a.w * b.w;
        #pragma unroll
        for (int off = 16; off; off >>= 1)
            p += __shfl_xor(p, off);
        float mn   = fmaxf(m, p);
        float corr = __expf(m - mn);
        float w    = __expf(p - mn);
        denom = denom * corr + w;
        acc.x = acc.x * corr + a.x * w;
        acc.y = acc.y * corr + a.y * w;
        acc.z = acc.z * corr + a.z * w;
        acc.w = acc.w * corr + a.w * w;
        m = mn;
    }

    float inv = (end > beg) ? (1.0f / denom) : 0.f;
    float4 o = {acc.x * inv, acc.y * inv, acc.z * inv, acc.w * inv};
    *((float4*)(neigh + (size_t)node * H_DIM) + lane) = o;
}

// ---------------------------------------------------------------------------
// K5: h = neigh @ W (fp32, 32x128 block tile, 4x4 reg tile) + column partials.
// Block-level LDS reduction (stride-9 padded: lane stride 72 % 32 = 8 -> no
// 32-way conflicts; reads at stride 9 are conflict-free), one store/thread.
// ---------------------------------------------------------------------------
__global__ __launch_bounds__(256) void gemm_stats_kernel(
    const float* __restrict__ neigh,
    const float* __restrict__ W,
    float* __restrict__ h,
    float* __restrict__ partial)
{
    __shared__ float Ws[128][128];   // 64 KB
    __shared__ float As[32][128];    // 16 KB (reused for the final reduction)

    int t  = threadIdx.x;
    int tx = t & 31;
    int ty = t >> 5;

    for (int i = t; i < 128 * 128; i += 256)
        Ws[i >> 7][i & 127] = W[i];

    float csum[4] = {0.f, 0.f, 0.f, 0.f};
    float csq[4]  = {0.f, 0.f, 0.f, 0.f};

    for (int r0 = blockIdx.x * 32; r0 < N_NODES; r0 += gridDim.x * 32) {
        __syncthreads();
        for (int i = t; i < 32 * 128; i += 256) {
            int r = i >> 7, k = i & 127;
            int gr = r0 + r;
            As[r][k] = (gr < N_NODES) ? neigh[(size_t)gr * H_DIM + k] : 0.f;
        }
        __syncthreads();

        float acc[4][4];
        #pragma unroll
        for (int i = 0; i < 4; ++i)
            #pragma unroll
            for (int j = 0; j < 4; ++j)
                acc[i][j] = 0.f;

        #pragma unroll 8
        for (int k = 0; k < 128; ++k) {
            float4 w = *(const float4*)(&Ws[k][tx * 4]);
            #pragma unroll
            for (int i = 0; i < 4; ++i) {
                float a = As[ty * 4 + i][k];
                acc[i][0] += a * w.x;
                acc[i][1] += a * w.y;
                acc[i][2] += a * w.z;
                acc[i][3] += a * w.w;
            }
        }

        #pragma unroll
        for (int i = 0; i < 4; ++i) {
            int gr = r0 + ty * 4 + i;
            if (gr < N_NODES) {
                float4 out;
                out.x = acc[i][0]; out.y = acc[i][1];
                out.z = acc[i][2]; out.w = acc[i][3];
                *(float4*)(h + (size_t)gr * H_DIM + tx * 4) = out;
                #pragma unroll
                for (int j = 0; j < 4; ++j) {
                    csum[j] += acc[i][j];
                    csq[j]  += acc[i][j] * acc[i][j];
                }
            }
        }
    }

    // ---- block-level reduction of csum/csq across ty (padded stride 9) ----
    __syncthreads();
    float* red = &As[0][0];          // needs 256*9 = 2304 floats, 4096 avail
    #pragma unroll
    for (int j = 0; j < 4; ++j) {
        red[(tx * 8 + j) * 9 + ty]       = csum[j];
        red[(tx * 8 + 4 + j) * 9 + ty]   = csq[j];
    }
    __syncthreads();
    float s = 0.f;
    #pragma unroll
    for (int q = 0; q < 8; ++q)
        s += red[t * 9 + q];
    partial[(size_t)blockIdx.x * 256 + t] = s;   // coalesced plain store
}

// ---------------------------------------------------------------------------
// K6: sum partials, fold BN stats into per-column scale/shift. One block.
// ---------------------------------------------------------------------------
__global__ __launch_bounds__(256) void bn_stats_kernel(
    const float* __restrict__ partial,
    const float* __restrict__ gamma,
    const float* __restrict__ beta,
    float* __restrict__ scale,
    float* __restrict__ shift)
{
    __shared__ float tot[256];
    int v = threadIdx.x;
    float s = 0.f;
    #pragma unroll 8
    for (int b = 0; b < GEMM_GRID; ++b)
        s += partial[(size_t)b * 256 + v];     // coalesced, L2-resident
    tot[v] = s;
    __syncthreads();
    if (v < 128) {
        int c = v;
        int base = (c >> 2) * 8 + (c & 3);
        float cs = tot[base];
        float cq = tot[base + 4];
        const float invN = 1.0f / (float)N_NODES;
        float mu  = cs * invN;
        float var = cq * invN - mu * mu;       // biased, matches jnp.var
        float sc  = gamma[c] * rsqrtf(var + BN_EPS);
        scale[c] = sc;
        shift[c] = beta[c] - mu * sc;
    }
}

// ---------------------------------------------------------------------------
// K7: out = tanh(h*scale + shift), in place
// ---------------------------------------------------------------------------
__global__ __launch_bounds__(256) void bn_tanh_kernel(
    float* __restrict__ h,
    const float* __restrict__ scale,
    const float* __restrict__ shift)
{
    size_t i = (size_t)blockIdx.x * blockDim.x + threadIdx.x;
    size_t idx4 = i * 4;
    if (idx4 >= (size_t)N_NODES * H_DIM) return;
    int c = (int)(idx4 & (H_DIM - 1));
    float4 v = *(float4*)(h + idx4);
    v.x = tanhf(v.x * scale[c + 0] + shift[c + 0]);
    v.y = tanhf(v.y * scale[c + 1] + shift[c + 1]);
    v.z = tanhf(v.z * scale[c + 2] + shift[c + 2]);
    v.w = tanhf(v.w * scale[c + 3] + shift[c + 3]);
    *(float4*)(h + idx4) = v;
}

// ---------------------------------------------------------------------------
extern "C" void kernel_launch(void* const* d_in, const int* in_sizes, int n_in,
                              void* d_out, int out_size, void* d_ws, size_t ws_size,
                              hipStream_t stream)
{
    const float* ent_emb = (const float*)d_in[0];
    const float* neigh_w = (const float*)d_in[1];
    const float* gamma   = (const float*)d_in[2];
    const float* beta    = (const float*)d_in[3];
    const int*   src     = (const int*)d_in[4];
    const int*   dst     = (const int*)d_in[5];
    float* out = (float*)d_out;

    char* ws = (char*)d_ws;
    float* neigh    = (float*)ws;                                    // 25.6 MB
    int*   deg      = (int*)(ws + (size_t)N_NODES * H_DIM * 4);      // 50000
    int*   rowptr   = deg + N_NODES;                                 // 50001
    int*   cursor   = rowptr + N_NODES + 1;                          // 50000
    int*   csr_src  = cursor + N_NODES;                              // 500000
    int*   blocksum = csr_src + N_EDGES;                             // 196
    int*   blockoff = blocksum + SCAN_NBLK;                          // 196
    float* partial  = (float*)(blockoff + SCAN_NBLK);                // 512*256
    float* scale    = partial + (size_t)GEMM_GRID * 256;
    float* shift    = scale + H_DIM;

    hipMemsetAsync(deg, 0, N_NODES * sizeof(int), stream);

    // CSR build (counting sort by dst); hierarchical 3-kernel scan
    hist_kernel<<<(N_EDGES + 255) / 256, 256, 0, stream>>>(dst, deg);
    scan_partial_kernel<<<SCAN_NBLK, 256, 0, stream>>>(deg, blocksum);
    scan_blocksums_kernel<<<1, 256, 0, stream>>>(blocksum, blockoff);
    scan_final_kernel<<<SCAN_NBLK, 256, 0, stream>>>(deg, blockoff, rowptr, cursor);
    csr_scatter_kernel<<<(N_EDGES + 255) / 256, 256, 0, stream>>>(src, dst, cursor, csr_src);

    // fused dot + online softmax + aggregate (one store per lane, no atomics)
    node_aggregate_kernel<<<(N_NODES + 7) / 8, 256, 0, stream>>>(
        ent_emb, rowptr, csr_src, neigh);

    // h = neigh @ W + column partials, then BN + tanh
    gemm_stats_kernel<<<GEMM_GRID, 256, 0, stream>>>(neigh, neigh_w, out, partial);
    bn_stats_kernel<<<1, 256, 0, stream>>>(partial, gamma, beta, scale, shift);
    {
        size_t total4 = (size_t)N_NODES * H_DIM / 4;
        int blocks = (int)((total4 + 255) / 256);
        bn_tanh_kernel<<<blocks, 256, 0, stream>>>(out, scale, shift);
    }
}